// Round 2
// baseline (1265.361 us; speedup 1.0000x reference)
//
#include <hip/hip_runtime.h>

// Problem constants (fixed by the reference).
#define ICn 16
#define OCn 16
#define Bn  32
#define Kn  65536       // (M-1)*(N-1) = 256*256
#define En  131584      // M*(N-1) + N*(M-1) = 257*256*2
#define VOFF 65792      // M*(N-1): start of vertical-edge region
#define KB  32          // k's per block (256 % 32 == 0 -> block stays in one row)

// out[b,o,k] = bias[o] + sum_{i,t} W[o,i,k,t] * x[b,i,col(k,t)]
// cols: c0=k, c1=k+256, c2=VOFF+row*257+j, c3=c2+1  (row=k/256, j=k%256)
__global__ __launch_bounds__(256, 2)
void e2i_kernel(const float* __restrict__ x,
                const float* __restrict__ w,
                const float* __restrict__ bias,
                float* __restrict__ out)
{
    const int tid = threadIdx.x;
    const int tk  = tid & 31;      // 0..31 : k within block (fast dim -> coalesced)
    const int tb  = tid >> 5;      // 0..7  : base batch lane
    const int k0  = blockIdx.x * KB;
    const int row = k0 >> 8;               // uniform across block
    const int j   = (k0 & 255) + tk;
    const int k   = k0 + tk;

    const int c0 = k;
    const int c1 = k + 256;
    const int c2 = VOFF + row * 257 + j;   // c3 = c2 + 1

    const float4* __restrict__ w4 = (const float4*)w;  // [(o*IC+i)*Kn + k] -> t0..t3

    #pragma unroll
    for (int bo = 0; bo < 2; ++bo) {
        const int bA = tb + bo * 8;        // b-pair: share each W load across 2 batches
        const int bB = bA + 16;

        float4 xA[ICn], xB[ICn];
        const float* pxA = x + (size_t)bA * (ICn * (size_t)En);
        const float* pxB = x + (size_t)bB * (ICn * (size_t)En);
        #pragma unroll
        for (int i = 0; i < ICn; ++i) {
            const float* pa = pxA + i * En;
            xA[i].x = pa[c0]; xA[i].y = pa[c1]; xA[i].z = pa[c2]; xA[i].w = pa[c2 + 1];
            const float* pb = pxB + i * En;
            xB[i].x = pb[c0]; xB[i].y = pb[c1]; xB[i].z = pb[c2]; xB[i].w = pb[c2 + 1];
        }

        for (int o = 0; o < OCn; ++o) {
            float accA = bias[o];
            float accB = accA;
            const float4* wp = w4 + (size_t)(o * ICn) * Kn + k;
            #pragma unroll
            for (int i = 0; i < ICn; ++i) {
                const float4 ww = wp[(size_t)i * Kn];
                accA += ww.x * xA[i].x + ww.y * xA[i].y + ww.z * xA[i].z + ww.w * xA[i].w;
                accB += ww.x * xB[i].x + ww.y * xB[i].y + ww.z * xB[i].z + ww.w * xB[i].w;
            }
            out[((size_t)bA * OCn + o) * Kn + k] = accA;
            out[((size_t)bB * OCn + o) * Kn + k] = accB;
        }
    }
}

extern "C" void kernel_launch(void* const* d_in, const int* in_sizes, int n_in,
                              void* d_out, int out_size, void* d_ws, size_t ws_size,
                              hipStream_t stream) {
    const float* x    = (const float*)d_in[0];   // (B, IC, E) fp32
    const float* wgt  = (const float*)d_in[1];   // (OC, IC, 4K) fp32
    const float* bias = (const float*)d_in[2];   // (OC,) fp32
    float* out = (float*)d_out;                  // (B, OC, K) fp32

    dim3 grid(Kn / KB);   // 2048 blocks
    dim3 block(256);
    e2i_kernel<<<grid, block, 0, stream>>>(x, wgt, bias, out);
}